// Round 3
// baseline (434.936 us; speedup 1.0000x reference)
//
#include <hip/hip_runtime.h>

// LoKr: out = x @ (W + 2*scalar*(A kron B))^T  with B (16,1)
// => out[m,r] = (x@W^T)[m,r] + 2*scalar*B[r&15] * (x@A^T)[m, r>>4]
//
// R3: barrier-free wave-autonomous streaming GEMM.
//  - mfma_f32_32x32x16_bf16; W loaded straight into B-fragment layout
//    (lane reads 8 contiguous floats of row r0+wv*32+(lane&31)), converted
//    fp32->bf16 in registers. No LDS at all, zero __syncthreads in K-loop.
//  - x pre-swizzled (convert kernel) into A-frag stream order: main loop
//    reads each frag at base+lane*16 (1KB/wave coalesced, L2-resident).
//  - y2 = x@A^T folded in as a second MFMA per (step,mt) with a B-frag of
//    A-rows arranged so accY is lane/reg-aligned with accW (no shuffles).
//  - KSPLIT=8 (512 blocks = 2/CU), fp32 partials in ws, final reduce.

#define M_DIM 128
#define N_DIM 8192
#define K_DIM 8192
#define KSPLIT 8
#define KCHUNK (K_DIM / KSPLIT)   // 1024
#define STEPS (KCHUNK / 16)       // 64 k-steps of 16

typedef __attribute__((ext_vector_type(8))) short bf16x8;    // MFMA A/B frag (4 VGPRs)
typedef __attribute__((ext_vector_type(16))) float f32x16;   // 32x32 acc (16 VGPRs)

__device__ __forceinline__ unsigned short f2bf(float f) {
  unsigned u = __builtin_bit_cast(unsigned, f);
  u += 0x7FFFu + ((u >> 16) & 1u);
  return (unsigned short)(u >> 16);
}

__device__ __forceinline__ bf16x8 pack8(float4 a, float4 b) {
  bf16x8 r;
  r[0] = (short)f2bf(a.x); r[1] = (short)f2bf(a.y);
  r[2] = (short)f2bf(a.z); r[3] = (short)f2bf(a.w);
  r[4] = (short)f2bf(b.x); r[5] = (short)f2bf(b.y);
  r[6] = (short)f2bf(b.z); r[7] = (short)f2bf(b.w);
  return r;
}

// Pre-swizzle x into A-fragment stream order for mfma_32x32x16:
// elem index ((sg*4+mt)*64 + lane)*8 + j  <-  x[mt*32+(lane&31)][sg*16+(lane>>5)*8+j]
__global__ void convert_x_kernel(const float* __restrict__ x,
                                 unsigned short* __restrict__ xs) {
  int tid = blockIdx.x * blockDim.x + threadIdx.x;   // 131072 threads
  int sg   = tid >> 8;
  int rem  = tid & 255;
  int mt   = rem >> 6;
  int lane = rem & 63;
  int m  = mt * 32 + (lane & 31);
  int kk = sg * 16 + (lane >> 5) * 8;
  const float* src = x + (size_t)m * K_DIM + kk;
  float4 a = *(const float4*)src;
  float4 b = *(const float4*)(src + 4);
  bf16x8 o = pack8(a, b);
  *(bf16x8*)(xs + (size_t)tid * 8) = o;
}

__global__ __launch_bounds__(256, 2) void lokr_main(
    const float* __restrict__ W,          // 8192 x 8192
    const float* __restrict__ A,          // 512 x 8192
    const float* __restrict__ Bv,         // 16
    const float* __restrict__ scal,       // 1
    const unsigned short* __restrict__ xs,// x swizzled to A-frag stream (bf16)
    float* __restrict__ part)             // [KSPLIT][128][8192] fp32 partials
{
  const int t    = threadIdx.x;
  const int lane = t & 63;
  const int wv   = t >> 6;                 // wave 0..3: W rows r0+wv*32 .. +31
  const int bx   = blockIdx.x;
  const int ks   = bx & (KSPLIT - 1);      // == XCD id under bx%8 dispatch
  const int ntb  = bx >> 3;                // n-tile 0..63
  const int r0   = ntb * 128;
  const int kbase = ks * KCHUNK;
  const int l31  = lane & 31;
  const int khalf = (lane >> 5) * 8;       // 0 or 8

  const int wrow = r0 + wv * 32 + l31;                 // this lane's W row (B-frag col)
  const int ia   = (r0 >> 4) + 2 * wv + (l31 >> 4);    // A row s.t. accY aligns with accW
  const float sB = 2.0f * scal[0] * Bv[lane & 15];

  const float* Wp = W + (size_t)wrow * K_DIM + kbase + khalf;
  const float* Ap = A + (size_t)ia  * K_DIM + kbase + khalf;
  // x frag stream: bytes base = (ks*STEPS + s)*4096 + mt*1024 + lane*16
  const unsigned short* Xp = xs + (size_t)(ks * STEPS) * 2048 + (size_t)lane * 8;

  f32x16 accW[4], accY[4];
#pragma unroll
  for (int mt = 0; mt < 4; ++mt) {
#pragma unroll
    for (int e = 0; e < 16; ++e) { accW[mt][e] = 0.f; accY[mt][e] = 0.f; }
  }

  // prologue: step-0 W/A in registers
  float4 wc0 = *(const float4*)Wp;
  float4 wc1 = *(const float4*)(Wp + 4);
  float4 ac0 = *(const float4*)Ap;
  float4 ac1 = *(const float4*)(Ap + 4);

  for (int s = 0; s < STEPS; ++s) {
    // issue next step's W/A loads (wrap on last iter: harmless re-load of step 0)
    const int sn = (s + 1) & (STEPS - 1);
    float4 wn0 = *(const float4*)(Wp + sn * 16);
    float4 wn1 = *(const float4*)(Wp + sn * 16 + 4);
    float4 an0 = *(const float4*)(Ap + sn * 16);
    float4 an1 = *(const float4*)(Ap + sn * 16 + 4);

    // x A-frags (coalesced 16B/lane, L2-resident)
    bf16x8 xf[4];
#pragma unroll
    for (int mt = 0; mt < 4; ++mt)
      xf[mt] = *(const bf16x8*)(Xp + (size_t)s * 2048 + mt * 512);

    bf16x8 bw = pack8(wc0, wc1);
    bf16x8 ba = pack8(ac0, ac1);

#pragma unroll
    for (int mt = 0; mt < 4; ++mt)
      accW[mt] = __builtin_amdgcn_mfma_f32_32x32x16_bf16(xf[mt], bw, accW[mt], 0, 0, 0);
#pragma unroll
    for (int mt = 0; mt < 4; ++mt)
      accY[mt] = __builtin_amdgcn_mfma_f32_32x32x16_bf16(xf[mt], ba, accY[mt], 0, 0, 0);

    wc0 = wn0; wc1 = wn1; ac0 = an0; ac1 = an1;
  }

  // epilogue: C/D layout col=lane&31, row=(reg&3)+8*(reg>>2)+4*(lane>>5)
  // accY[mt][reg] holds y2[m][ia] for the SAME (m, lane) -> no shuffle.
  float* p = part + (size_t)ks * M_DIM * N_DIM + r0 + wv * 32 + l31;
#pragma unroll
  for (int mt = 0; mt < 4; ++mt) {
#pragma unroll
    for (int reg = 0; reg < 16; ++reg) {
      int m = mt * 32 + (reg & 3) + 8 * (reg >> 2) + 4 * (lane >> 5);
      p[(size_t)m * N_DIM] = accW[mt][reg] + sB * accY[mt][reg];
    }
  }
}

__global__ void reduce_kernel(const float4* __restrict__ part,
                              float4* __restrict__ out) {
  int t = blockIdx.x * blockDim.x + threadIdx.x;
  const int n4 = M_DIM * N_DIM / 4;  // 262144
  for (int i = t; i < n4; i += gridDim.x * blockDim.x) {
    float4 s = part[i];
#pragma unroll
    for (int ksp = 1; ksp < KSPLIT; ++ksp) {
      float4 v = part[(size_t)ksp * n4 + i];
      s.x += v.x; s.y += v.y; s.z += v.z; s.w += v.w;
    }
    out[i] = s;
  }
}

extern "C" void kernel_launch(void* const* d_in, const int* in_sizes, int n_in,
                              void* d_out, int out_size, void* d_ws, size_t ws_size,
                              hipStream_t stream) {
  const float* x    = (const float*)d_in[0];   // 128 x 8192
  const float* W    = (const float*)d_in[1];   // 8192 x 8192
  const float* A    = (const float*)d_in[2];   // 512 x 8192
  const float* Bv   = (const float*)d_in[3];   // 16
  const float* scal = (const float*)d_in[4];   // 1
  float* out = (float*)d_out;

  // ws: [0,2MB) x swizzled bf16; [2MB, 2MB+32MB) fp32 partials [KSPLIT][128][8192]
  unsigned short* xs = (unsigned short*)d_ws;
  float* part = (float*)((char*)d_ws + (size_t)M_DIM * K_DIM * sizeof(unsigned short));

  convert_x_kernel<<<512, 256, 0, stream>>>(x, xs);
  lokr_main<<<(N_DIM / 128) * KSPLIT, 256, 0, stream>>>(W, A, Bv, scal, xs, part);
  reduce_kernel<<<1024, 256, 0, stream>>>((const float4*)part, (float4*)out);
}